// Round 2
// baseline (356.448 us; speedup 1.0000x reference)
//
#include <hip/hip_runtime.h>
#include <hip/hip_bf16.h>
#include <math.h>

// Problem: CausalSelfAttention  B=4 T=2048 D=1024 H=16 HD=64
// d_in: fp32 x[4,2048,1024], Wq,Wk,Wv,Wp[1024,1024], bp[1024]; d_out: fp32 y.
// Pipeline: cvt(fp32->bf16 into ws) -> qkv -> attn -> proj.
// ws layout (bf16 elems): XB[8.39M] (reused as Y after qkv) | WQB,WKB,WVB,WPB[1M each] | Q,K,V[8.39M each]
// total = 75.3 MB

#define B_  4
#define T_  2048
#define D_  1024
#define H_  16
#define HD_ 64
#define M_  (B_ * T_)   // 8192 rows

typedef short bf16x8 __attribute__((ext_vector_type(8)));
typedef float f32x4  __attribute__((ext_vector_type(4)));

__device__ __forceinline__ f32x4 mfma16(bf16x8 a, bf16x8 b, f32x4 c) {
    return __builtin_amdgcn_mfma_f32_16x16x32_bf16(a, b, c, 0, 0, 0);
}

__device__ __forceinline__ void gl_lds16(const unsigned short* g, unsigned short* l) {
    __builtin_amdgcn_global_load_lds(
        (const __attribute__((address_space(1))) void*)g,
        (__attribute__((address_space(3))) void*)l, 16, 0, 0);
}

__device__ __forceinline__ unsigned short f2bf(float f) {
    union { __hip_bfloat16 h; unsigned short u; } cv;
    cv.h = __float2bfloat16(f);
    return cv.u;
}
__device__ __forceinline__ float bf2f(unsigned short u) {
    return __uint_as_float(((unsigned)u) << 16);
}

struct su4 { unsigned short x, y, z, w; };

// ---------------------------------------------------------------------------
// fp32 -> bf16 conversion, 4 elems/thread, vectorized.
// ---------------------------------------------------------------------------
__global__ __launch_bounds__(256)
void cvt_kernel(const float* __restrict__ in, unsigned short* __restrict__ out) {
    const int i = blockIdx.x * 256 + threadIdx.x;
    const float4 v = ((const float4*)in)[i];
    su4 o;
    o.x = f2bf(v.x); o.y = f2bf(v.y); o.z = f2bf(v.z); o.w = f2bf(v.w);
    ((su4*)out)[i] = o;
}

// ---------------------------------------------------------------------------
// Fused QKV GEMM:  C = X @ W^T  (bf16 in ws), m97-like 128x128 tile, BK=64.
// blockIdx.y: 0..7 -> Wq, 8..15 -> Wk, 16..23 -> Wv; n0 = (by&7)*128.
// Output scattered to [B,H,T,HD] head-major bf16.
// ---------------------------------------------------------------------------
__global__ __launch_bounds__(256, 2)
void qkv_kernel(const unsigned short* __restrict__ X,
                const unsigned short* __restrict__ Wq,
                const unsigned short* __restrict__ Wk,
                const unsigned short* __restrict__ Wv,
                unsigned short* __restrict__ Qo,
                unsigned short* __restrict__ Ko,
                unsigned short* __restrict__ Vo)
{
    __shared__ unsigned short As[128 * 64];
    __shared__ unsigned short Bs[128 * 64];

    const int m0 = blockIdx.x * 128;
    const int by = blockIdx.y;
    const unsigned short* W = (by < 8) ? Wq : (by < 16) ? Wk : Wv;
    unsigned short*       O = (by < 8) ? Qo : (by < 16) ? Ko : Vo;
    const int n0   = (by & 7) * 128;
    const int tid  = threadIdx.x;
    const int lane = tid & 63;
    const int wv   = tid >> 6;
    const int wr   = (wv >> 1) * 64;
    const int wc   = (wv & 1) * 64;
    const int g    = lane >> 4;
    const int c    = lane & 15;

    f32x4 acc[4][4] = {};

    for (int k0 = 0; k0 < D_; k0 += 64) {
        #pragma unroll
        for (int i = 0; i < 4; ++i) {
            const int flat = i * 2048 + tid * 8;
            const int row = flat >> 6, col = flat & 63;
            gl_lds16(X + (size_t)(m0 + row) * D_ + k0 + col, As + flat);
            gl_lds16(W + (size_t)(n0 + row) * D_ + k0 + col, Bs + flat);
        }
        __syncthreads();
        #pragma unroll
        for (int kk = 0; kk < 64; kk += 32) {
            bf16x8 af[4], bg[4];
            #pragma unroll
            for (int mi = 0; mi < 4; ++mi)
                af[mi] = *(const bf16x8*)(As + (wr + mi * 16 + c) * 64 + kk + g * 8);
            #pragma unroll
            for (int ni = 0; ni < 4; ++ni)
                bg[ni] = *(const bf16x8*)(Bs + (wc + ni * 16 + c) * 64 + kk + g * 8);
            #pragma unroll
            for (int mi = 0; mi < 4; ++mi)
                #pragma unroll
                for (int ni = 0; ni < 4; ++ni)
                    acc[mi][ni] = mfma16(af[mi], bg[ni], acc[mi][ni]);
        }
        __syncthreads();
    }

    #pragma unroll
    for (int mi = 0; mi < 4; ++mi) {
        #pragma unroll
        for (int ni = 0; ni < 4; ++ni) {
            #pragma unroll
            for (int r = 0; r < 4; ++r) {
                const int m = m0 + wr + mi * 16 + g * 4 + r;
                const int n = n0 + wc + ni * 16 + c;
                const int b = m >> 11, t = m & (T_ - 1);
                const int h = n >> 6,  hd = n & 63;
                O[((size_t)((b << 4) + h) * T_ + t) * HD_ + hd] = f2bf(acc[mi][ni][r]);
            }
        }
    }
}

// ---------------------------------------------------------------------------
// Causal flash attention.  Block = 4 waves, one (b,h), 64-row Q tile (16/wave).
// 32-key tiles: K frags from global (L2-resident), V^T staged in LDS,
// P via padded per-wave LDS. Y written bf16 row-major [8192,1024].
// ---------------------------------------------------------------------------
__global__ __launch_bounds__(256, 2)
void attn_kernel(const unsigned short* __restrict__ Q,
                 const unsigned short* __restrict__ K,
                 const unsigned short* __restrict__ V,
                 unsigned short* __restrict__ Y)
{
    __shared__ unsigned short Vt[64 * 40];
    __shared__ unsigned short Pl[64 * 40];

    const int bh = blockIdx.x;
    const int q0 = blockIdx.y * 64;
    const unsigned short* Qp = Q + (size_t)bh * T_ * HD_;
    const unsigned short* Kp = K + (size_t)bh * T_ * HD_;
    const unsigned short* Vp = V + (size_t)bh * T_ * HD_;

    const int tid  = threadIdx.x;
    const int lane = tid & 63;
    const int w    = tid >> 6;
    const int g    = lane >> 4;
    const int c    = lane & 15;
    const int qw   = q0 + w * 16;
    const int qmax = qw + 15;

    bf16x8 qf[2];
    #pragma unroll
    for (int dk = 0; dk < 2; ++dk)
        qf[dk] = *(const bf16x8*)(Qp + (size_t)(qw + c) * HD_ + dk * 32 + g * 8);

    const float NEG = -1e30f;
    float mrow[4] = {NEG, NEG, NEG, NEG};
    float lrow[4] = {0.f, 0.f, 0.f, 0.f};
    f32x4 oacc[4] = {};

    const int nt = (q0 + 64) >> 5;

    for (int kt = 0; kt < nt; ++kt) {
        const int tb = kt << 5;
        {
            const int t  = tid >> 3;
            const int d0 = (tid & 7) * 8;
            bf16x8 vv = *(const bf16x8*)(Vp + (size_t)(tb + t) * HD_ + d0);
            #pragma unroll
            for (int j = 0; j < 8; ++j)
                Vt[(d0 + j) * 40 + t] = (unsigned short)vv[j];
        }
        __syncthreads();

        if (tb <= qmax) {
            f32x4 s[2] = {};
            #pragma unroll
            for (int ni = 0; ni < 2; ++ni)
                #pragma unroll
                for (int dk = 0; dk < 2; ++dk) {
                    bf16x8 kf = *(const bf16x8*)(Kp + (size_t)(tb + ni * 16 + c) * HD_ + dk * 32 + g * 8);
                    s[ni] = mfma16(qf[dk], kf, s[ni]);
                }

            float pvv[2][4];
            float tmax[4] = {NEG, NEG, NEG, NEG};
            #pragma unroll
            for (int ni = 0; ni < 2; ++ni)
                #pragma unroll
                for (int r = 0; r < 4; ++r) {
                    float val = s[ni][r] * 0.125f;
                    const int q = qw + g * 4 + r;
                    const int t = tb + ni * 16 + c;
                    val = (t <= q) ? val : NEG;
                    pvv[ni][r] = val;
                    tmax[r] = fmaxf(tmax[r], val);
                }
            #pragma unroll
            for (int mk = 1; mk < 16; mk <<= 1)
                #pragma unroll
                for (int r = 0; r < 4; ++r)
                    tmax[r] = fmaxf(tmax[r], __shfl_xor(tmax[r], mk));

            float al[4];
            #pragma unroll
            for (int r = 0; r < 4; ++r) {
                const float mn = fmaxf(mrow[r], tmax[r]);
                al[r] = __expf(mrow[r] - mn);
                mrow[r] = mn;
            }

            float rsum[4] = {0.f, 0.f, 0.f, 0.f};
            #pragma unroll
            for (int ni = 0; ni < 2; ++ni)
                #pragma unroll
                for (int r = 0; r < 4; ++r) {
                    const float e = __expf(pvv[ni][r] - mrow[r]);
                    Pl[(w * 16 + g * 4 + r) * 40 + ni * 16 + c] = f2bf(e);
                    rsum[r] += e;
                }
            #pragma unroll
            for (int mk = 1; mk < 16; mk <<= 1)
                #pragma unroll
                for (int r = 0; r < 4; ++r)
                    rsum[r] += __shfl_xor(rsum[r], mk);

            #pragma unroll
            for (int r = 0; r < 4; ++r)
                lrow[r] = lrow[r] * al[r] + rsum[r];
            #pragma unroll
            for (int dn = 0; dn < 4; ++dn)
                #pragma unroll
                for (int r = 0; r < 4; ++r)
                    oacc[dn][r] *= al[r];

            bf16x8 pf = *(const bf16x8*)(Pl + (w * 16 + c) * 40 + g * 8);
            #pragma unroll
            for (int dn = 0; dn < 4; ++dn) {
                bf16x8 vf = *(const bf16x8*)(Vt + (dn * 16 + c) * 40 + g * 8);
                oacc[dn] = mfma16(pf, vf, oacc[dn]);
            }
        }
        __syncthreads();
    }

    const int b = bh >> 4, h = bh & 15;
    #pragma unroll
    for (int dn = 0; dn < 4; ++dn)
        #pragma unroll
        for (int r = 0; r < 4; ++r) {
            const int q = qw + g * 4 + r;
            const float o = oacc[dn][r] / lrow[r];
            const int col = h * 64 + dn * 16 + c;
            Y[(size_t)(b * T_ + q) * D_ + col] = f2bf(o);
        }
}

// ---------------------------------------------------------------------------
// Output projection:  out = Y @ Wp^T + bp.  Y bf16[8192,1024]; out fp32.
// ---------------------------------------------------------------------------
__global__ __launch_bounds__(256, 2)
void proj_kernel(const unsigned short* __restrict__ Yin,
                 const unsigned short* __restrict__ Wp,
                 const float* __restrict__ bp,
                 float* __restrict__ Out)
{
    __shared__ unsigned short As[128 * 64];
    __shared__ unsigned short Bs[128 * 64];

    const int m0 = blockIdx.x * 128;
    const int n0 = blockIdx.y * 128;
    const int tid  = threadIdx.x;
    const int lane = tid & 63;
    const int wv   = tid >> 6;
    const int wr   = (wv >> 1) * 64;
    const int wc   = (wv & 1) * 64;
    const int g    = lane >> 4;
    const int c    = lane & 15;

    f32x4 acc[4][4] = {};

    for (int k0 = 0; k0 < D_; k0 += 64) {
        #pragma unroll
        for (int i = 0; i < 4; ++i) {
            const int flat = i * 2048 + tid * 8;
            const int row = flat >> 6, col = flat & 63;
            gl_lds16(Yin + (size_t)(m0 + row) * D_ + k0 + col, As + flat);
            gl_lds16(Wp  + (size_t)(n0 + row) * D_ + k0 + col, Bs + flat);
        }
        __syncthreads();
        #pragma unroll
        for (int kk = 0; kk < 64; kk += 32) {
            bf16x8 af[4], bg[4];
            #pragma unroll
            for (int mi = 0; mi < 4; ++mi)
                af[mi] = *(const bf16x8*)(As + (wr + mi * 16 + c) * 64 + kk + g * 8);
            #pragma unroll
            for (int ni = 0; ni < 4; ++ni)
                bg[ni] = *(const bf16x8*)(Bs + (wc + ni * 16 + c) * 64 + kk + g * 8);
            #pragma unroll
            for (int mi = 0; mi < 4; ++mi)
                #pragma unroll
                for (int ni = 0; ni < 4; ++ni)
                    acc[mi][ni] = mfma16(af[mi], bg[ni], acc[mi][ni]);
        }
        __syncthreads();
    }

    #pragma unroll
    for (int mi = 0; mi < 4; ++mi) {
        #pragma unroll
        for (int ni = 0; ni < 4; ++ni) {
            const int n = n0 + wc + ni * 16 + c;
            const float bb = bp[n];
            #pragma unroll
            for (int r = 0; r < 4; ++r) {
                const int m = m0 + wr + mi * 16 + g * 4 + r;
                Out[(size_t)m * D_ + n] = acc[mi][ni][r] + bb;
            }
        }
    }
}

// ---------------------------------------------------------------------------
extern "C" void kernel_launch(void* const* d_in, const int* in_sizes, int n_in,
                              void* d_out, int out_size, void* d_ws, size_t ws_size,
                              hipStream_t stream) {
    const float* x  = (const float*)d_in[0];
    const float* Wq = (const float*)d_in[1];
    const float* Wk = (const float*)d_in[2];
    const float* Wv = (const float*)d_in[3];
    const float* Wp = (const float*)d_in[4];
    const float* bp = (const float*)d_in[5];
    float* out = (float*)d_out;

    const size_t SZ = (size_t)M_ * D_;       // 8388608
    const size_t WSZ = (size_t)D_ * D_;      // 1048576
    unsigned short* ws = (unsigned short*)d_ws;
    unsigned short* XB  = ws;                 // also Y after qkv
    unsigned short* WQB = XB  + SZ;
    unsigned short* WKB = WQB + WSZ;
    unsigned short* WVB = WKB + WSZ;
    unsigned short* WPB = WVB + WSZ;
    unsigned short* Qw  = WPB + WSZ;
    unsigned short* Kw  = Qw + SZ;
    unsigned short* Vw  = Kw + SZ;
    unsigned short* Yw  = XB;                 // overlay: x_bf16 dead after qkv

    dim3 blk(256);
    cvt_kernel<<<dim3(SZ / 1024),  blk, 0, stream>>>(x,  XB);
    cvt_kernel<<<dim3(WSZ / 1024), blk, 0, stream>>>(Wq, WQB);
    cvt_kernel<<<dim3(WSZ / 1024), blk, 0, stream>>>(Wk, WKB);
    cvt_kernel<<<dim3(WSZ / 1024), blk, 0, stream>>>(Wv, WVB);
    cvt_kernel<<<dim3(WSZ / 1024), blk, 0, stream>>>(Wp, WPB);

    qkv_kernel <<<dim3(M_ / 128, 24), blk, 0, stream>>>(XB, WQB, WKB, WVB, Qw, Kw, Vw);
    attn_kernel<<<dim3(B_ * H_, T_ / 64), blk, 0, stream>>>(Qw, Kw, Vw, Yw);
    proj_kernel<<<dim3(M_ / 128, D_ / 128), blk, 0, stream>>>(Yw, WPB, bp, out);
}

// Round 4
// 289.472 us; speedup vs baseline: 1.2314x; 1.2314x over previous
//
#include <hip/hip_runtime.h>
#include <hip/hip_bf16.h>
#include <math.h>

// Problem: CausalSelfAttention  B=4 T=2048 D=1024 H=16 HD=64
// d_in: fp32 x[4,2048,1024], Wq,Wk,Wv,Wp[1024,1024], bp[1024]; d_out: fp32 y.
// Pipeline: cvt(fp32->bf16 into ws) -> qkv -> attn -> proj.

#define B_  4
#define T_  2048
#define D_  1024
#define H_  16
#define HD_ 64
#define M_  (B_ * T_)   // 8192 rows

typedef short bf16x8 __attribute__((ext_vector_type(8)));
typedef float f32x4  __attribute__((ext_vector_type(4)));

__device__ __forceinline__ f32x4 mfma16(bf16x8 a, bf16x8 b, f32x4 c) {
    return __builtin_amdgcn_mfma_f32_16x16x32_bf16(a, b, c, 0, 0, 0);
}

__device__ __forceinline__ void gl_lds16(const unsigned short* g, unsigned short* l) {
    __builtin_amdgcn_global_load_lds(
        (const __attribute__((address_space(1))) void*)g,
        (__attribute__((address_space(3))) void*)l, 16, 0, 0);
}

__device__ __forceinline__ unsigned short f2bf(float f) {
    union { __hip_bfloat16 h; unsigned short u; } cv;
    cv.h = __float2bfloat16(f);
    return cv.u;
}
__device__ __forceinline__ float bf2f(unsigned short u) {
    return __uint_as_float(((unsigned)u) << 16);
}
__device__ __forceinline__ float exp2_fast(float x) {
    return __builtin_amdgcn_exp2f(x);   // v_exp_f32: 2^x
}

struct su4 { unsigned short x, y, z, w; };

// ---------------------------------------------------------------------------
__global__ __launch_bounds__(256)
void cvt_kernel(const float* __restrict__ in, unsigned short* __restrict__ out) {
    const int i = blockIdx.x * 256 + threadIdx.x;
    const float4 v = ((const float4*)in)[i];
    su4 o;
    o.x = f2bf(v.x); o.y = f2bf(v.y); o.z = f2bf(v.z); o.w = f2bf(v.w);
    ((su4*)out)[i] = o;
}

// ---------------------------------------------------------------------------
// Fused QKV GEMM (verified structure): C = X @ W^T, out scattered [B,H,T,HD].
// ---------------------------------------------------------------------------
__global__ __launch_bounds__(256, 2)
void qkv_kernel(const unsigned short* __restrict__ X,
                const unsigned short* __restrict__ Wq,
                const unsigned short* __restrict__ Wk,
                const unsigned short* __restrict__ Wv,
                unsigned short* __restrict__ Qo,
                unsigned short* __restrict__ Ko,
                unsigned short* __restrict__ Vo)
{
    __shared__ unsigned short As[128 * 64];
    __shared__ unsigned short Bs[128 * 64];

    const int m0 = blockIdx.x * 128;
    const int by = blockIdx.y;
    const unsigned short* W = (by < 8) ? Wq : (by < 16) ? Wk : Wv;
    unsigned short*       O = (by < 8) ? Qo : (by < 16) ? Ko : Vo;
    const int n0   = (by & 7) * 128;
    const int tid  = threadIdx.x;
    const int lane = tid & 63;
    const int wv   = tid >> 6;
    const int wr   = (wv >> 1) * 64;
    const int wc   = (wv & 1) * 64;
    const int g    = lane >> 4;
    const int c    = lane & 15;

    f32x4 acc[4][4] = {};

    for (int k0 = 0; k0 < D_; k0 += 64) {
        #pragma unroll
        for (int i = 0; i < 4; ++i) {
            const int flat = i * 2048 + tid * 8;
            const int row = flat >> 6, col = flat & 63;
            gl_lds16(X + (size_t)(m0 + row) * D_ + k0 + col, As + flat);
            gl_lds16(W + (size_t)(n0 + row) * D_ + k0 + col, Bs + flat);
        }
        __syncthreads();
        #pragma unroll
        for (int kk = 0; kk < 64; kk += 32) {
            bf16x8 af[4], bg[4];
            #pragma unroll
            for (int mi = 0; mi < 4; ++mi)
                af[mi] = *(const bf16x8*)(As + (wr + mi * 16 + c) * 64 + kk + g * 8);
            #pragma unroll
            for (int ni = 0; ni < 4; ++ni)
                bg[ni] = *(const bf16x8*)(Bs + (wc + ni * 16 + c) * 64 + kk + g * 8);
            #pragma unroll
            for (int mi = 0; mi < 4; ++mi)
                #pragma unroll
                for (int ni = 0; ni < 4; ++ni)
                    acc[mi][ni] = mfma16(af[mi], bg[ni], acc[mi][ni]);
        }
        __syncthreads();
    }

    #pragma unroll
    for (int mi = 0; mi < 4; ++mi) {
        #pragma unroll
        for (int ni = 0; ni < 4; ++ni) {
            #pragma unroll
            for (int r = 0; r < 4; ++r) {
                const int m = m0 + wr + mi * 16 + g * 4 + r;
                const int n = n0 + wc + ni * 16 + c;
                const int b = m >> 11, t = m & (T_ - 1);
                const int h = n >> 6,  hd = n & 63;
                O[((size_t)((b << 4) + h) * T_ + t) * HD_ + hd] = f2bf(acc[mi][ni][r]);
            }
        }
    }
}

// ---------------------------------------------------------------------------
// Causal flash attention v2: barrier-free, no LDS.
//  - Block = 4 waves; handles Q-tiles pair and 31-pair (64 rows each) for one
//    (b,h): uniform work across blocks.
//  - Swapped QK^T: s = mfma(K,Q) -> lane holds S[t-part][q=lane&15];
//    softmax per-lane + 2 xor-shuffles.
//  - P transposed to PV A-operand via 8 __shfl + select.
//  - Swapped PV: oacc = mfma(V^T, P): output rows=d, col=q=lane&15 -> rescale
//    and 1/l are per-lane, no shuffles.
//  - V^T frags gathered directly from global (L2-resident), K frags b128.
// ---------------------------------------------------------------------------
__global__ __launch_bounds__(256, 4)
void attn_kernel(const unsigned short* __restrict__ Q,
                 const unsigned short* __restrict__ K,
                 const unsigned short* __restrict__ V,
                 unsigned short* __restrict__ Y)
{
    const int bh = blockIdx.x;          // 0..63
    const int pr = blockIdx.y;          // 0..15
    const unsigned short* Qp = Q + (size_t)bh * T_ * HD_;
    const unsigned short* Kp = K + (size_t)bh * T_ * HD_;
    const unsigned short* Vp = V + (size_t)bh * T_ * HD_;
    const int b = bh >> 4, h = bh & 15;

    const int lane = threadIdx.x & 63;
    const int w    = threadIdx.x >> 6;
    const int g    = lane >> 4;
    const int c    = lane & 15;
    const float SC = 0.18033688011112042f;   // (1/sqrt(64)) * log2(e)

    for (int hf = 0; hf < 2; ++hf) {
        const int qt = (hf ? 31 - pr : pr) * 64;
        const int qw = qt + w * 16;

        // Q as B-operand frags, pre-scaled (softmax scale folded, log2 domain)
        bf16x8 qf[2];
        #pragma unroll
        for (int dk = 0; dk < 2; ++dk) {
            bf16x8 t = *(const bf16x8*)(Qp + (size_t)(qw + c) * HD_ + dk * 32 + g * 8);
            #pragma unroll
            for (int j = 0; j < 8; ++j)
                t[j] = (short)f2bf(bf2f((unsigned short)t[j]) * SC);
            qf[dk] = t;
        }

        float m_l = -1e30f, l_l = 0.f;
        f32x4 oacc[4] = {};
        const int nfull = qw >> 5;

        auto tile = [&](int tb, bool masked) {
            // S^T = K Q^T : lane holds S[tb + ni*16 + g*4 + r][qw + c]
            f32x4 s[2] = {};
            #pragma unroll
            for (int ni = 0; ni < 2; ++ni)
                #pragma unroll
                for (int dk = 0; dk < 2; ++dk) {
                    bf16x8 kf = *(const bf16x8*)(Kp + (size_t)(tb + ni * 16 + c) * HD_ + dk * 32 + g * 8);
                    s[ni] = mfma16(kf, qf[dk], s[ni]);
                }

            // V^T A-operand frags: lane holds V[tb + g*8 + j][dn*16 + c]
            unsigned int vu[4][4];
            #pragma unroll
            for (int dn = 0; dn < 4; ++dn)
                #pragma unroll
                for (int jp = 0; jp < 4; ++jp) {
                    const unsigned int x0 = Vp[(size_t)(tb + g * 8 + jp * 2)     * HD_ + dn * 16 + c];
                    const unsigned int x1 = Vp[(size_t)(tb + g * 8 + jp * 2 + 1) * HD_ + dn * 16 + c];
                    vu[dn][jp] = x0 | (x1 << 16);
                }

            float p[2][4];
            #pragma unroll
            for (int ni = 0; ni < 2; ++ni)
                #pragma unroll
                for (int r = 0; r < 4; ++r)
                    p[ni][r] = s[ni][r];
            if (masked) {
                #pragma unroll
                for (int ni = 0; ni < 2; ++ni)
                    #pragma unroll
                    for (int r = 0; r < 4; ++r)
                        p[ni][r] = (tb + ni * 16 + g * 4 + r <= qw + c) ? p[ni][r] : -1e30f;
            }

            float pmax = p[0][0];
            #pragma unroll
            for (int ni = 0; ni < 2; ++ni)
                #pragma unroll
                for (int r = 0; r < 4; ++r)
                    pmax = fmaxf(pmax, p[ni][r]);
            pmax = fmaxf(pmax, __shfl_xor(pmax, 16));
            pmax = fmaxf(pmax, __shfl_xor(pmax, 32));

            const float mn = fmaxf(m_l, pmax);
            const float al = exp2_fast(m_l - mn);
            m_l = mn;

            float rs = 0.f;
            #pragma unroll
            for (int ni = 0; ni < 2; ++ni)
                #pragma unroll
                for (int r = 0; r < 4; ++r) {
                    const float e = exp2_fast(p[ni][r] - mn);
                    p[ni][r] = e;
                    rs += e;
                }
            rs += __shfl_xor(rs, 16);
            rs += __shfl_xor(rs, 32);
            l_l = l_l * al + rs;

            // pack P pairs: P32[ni][hp] holds k-local = ni*16 + g*4 + 2hp, +1
            unsigned int P32[2][2];
            #pragma unroll
            for (int ni = 0; ni < 2; ++ni)
                #pragma unroll
                for (int hp = 0; hp < 2; ++hp)
                    P32[ni][hp] = (unsigned int)f2bf(p[ni][2 * hp])
                                | ((unsigned int)f2bf(p[ni][2 * hp + 1]) << 16);

            // transpose: target lane (c,g) needs k = g*8 + j from lanes
            // sl0 = c + 32*(g&1) (j 0..3) and sl1 = sl0+16 (j 4..7), ni = g>>1
            const int sl0 = c + ((lane & 16) << 1);   // (g&1)<<5
            const int sl1 = sl0 + 16;
            const int q00 = __shfl((int)P32[0][0], sl0), q10 = __shfl((int)P32[1][0], sl0);
            const int q01 = __shfl((int)P32[0][1], sl0), q11 = __shfl((int)P32[1][1], sl0);
            const int q02 = __shfl((int)P32[0][0], sl1), q12 = __shfl((int)P32[1][0], sl1);
            const int q03 = __shfl((int)P32[0][1], sl1), q13 = __shfl((int)P32[1][1], sl1);
            const bool nhi = (g & 2) != 0;
            union { unsigned int u[4]; bf16x8 v; } pf;
            pf.u[0] = nhi ? q10 : q00;
            pf.u[1] = nhi ? q11 : q01;
            pf.u[2] = nhi ? q12 : q02;
            pf.u[3] = nhi ? q13 : q03;

            // rescale + PV (swapped): oacc rows = d, col = q = c (per-lane al)
            #pragma unroll
            for (int dn = 0; dn < 4; ++dn) {
                #pragma unroll
                for (int r = 0; r < 4; ++r)
                    oacc[dn][r] *= al;
                union { unsigned int u[4]; bf16x8 v; } vf;
                vf.u[0] = vu[dn][0]; vf.u[1] = vu[dn][1];
                vf.u[2] = vu[dn][2]; vf.u[3] = vu[dn][3];
                oacc[dn] = mfma16(vf.v, pf.v, oacc[dn]);
            }
        };

        for (int kt = 0; kt < nfull; ++kt) tile(kt << 5, false);
        tile(nfull << 5, true);

        // Epilogue: O[q = qw+c][d = dn*16 + g*4 + r], packed 8B stores
        const float li = 1.f / l_l;
        const size_t rowoff = (size_t)(b * T_ + qw + c) * D_ + h * 64;
        #pragma unroll
        for (int dn = 0; dn < 4; ++dn) {
            const unsigned int u0 = (unsigned int)f2bf(oacc[dn][0] * li)
                                  | ((unsigned int)f2bf(oacc[dn][1] * li) << 16);
            const unsigned int u1 = (unsigned int)f2bf(oacc[dn][2] * li)
                                  | ((unsigned int)f2bf(oacc[dn][3] * li) << 16);
            uint2 st; st.x = u0; st.y = u1;
            *(uint2*)(Y + rowoff + dn * 16 + g * 4) = st;
        }
    }
}

// ---------------------------------------------------------------------------
// Output projection:  out = Y @ Wp^T + bp.  Y bf16[8192,1024]; out fp32.
// ---------------------------------------------------------------------------
__global__ __launch_bounds__(256, 2)
void proj_kernel(const unsigned short* __restrict__ Yin,
                 const unsigned short* __restrict__ Wp,
                 const float* __restrict__ bp,
                 float* __restrict__ Out)
{
    __shared__ unsigned short As[128 * 64];
    __shared__ unsigned short Bs[128 * 64];

    const int m0 = blockIdx.x * 128;
    const int n0 = blockIdx.y * 128;
    const int tid  = threadIdx.x;
    const int lane = tid & 63;
    const int wv   = tid >> 6;
    const int wr   = (wv >> 1) * 64;
    const int wc   = (wv & 1) * 64;
    const int g    = lane >> 4;
    const int c    = lane & 15;

    f32x4 acc[4][4] = {};

    for (int k0 = 0; k0 < D_; k0 += 64) {
        #pragma unroll
        for (int i = 0; i < 4; ++i) {
            const int flat = i * 2048 + tid * 8;
            const int row = flat >> 6, col = flat & 63;
            gl_lds16(Yin + (size_t)(m0 + row) * D_ + k0 + col, As + flat);
            gl_lds16(Wp  + (size_t)(n0 + row) * D_ + k0 + col, Bs + flat);
        }
        __syncthreads();
        #pragma unroll
        for (int kk = 0; kk < 64; kk += 32) {
            bf16x8 af[4], bg[4];
            #pragma unroll
            for (int mi = 0; mi < 4; ++mi)
                af[mi] = *(const bf16x8*)(As + (wr + mi * 16 + c) * 64 + kk + g * 8);
            #pragma unroll
            for (int ni = 0; ni < 4; ++ni)
                bg[ni] = *(const bf16x8*)(Bs + (wc + ni * 16 + c) * 64 + kk + g * 8);
            #pragma unroll
            for (int mi = 0; mi < 4; ++mi)
                #pragma unroll
                for (int ni = 0; ni < 4; ++ni)
                    acc[mi][ni] = mfma16(af[mi], bg[ni], acc[mi][ni]);
        }
        __syncthreads();
    }

    #pragma unroll
    for (int mi = 0; mi < 4; ++mi) {
        #pragma unroll
        for (int ni = 0; ni < 4; ++ni) {
            const int n = n0 + wc + ni * 16 + c;
            const float bb = bp[n];
            #pragma unroll
            for (int r = 0; r < 4; ++r) {
                const int m = m0 + wr + mi * 16 + g * 4 + r;
                Out[(size_t)m * D_ + n] = acc[mi][ni][r] + bb;
            }
        }
    }
}

// ---------------------------------------------------------------------------
extern "C" void kernel_launch(void* const* d_in, const int* in_sizes, int n_in,
                              void* d_out, int out_size, void* d_ws, size_t ws_size,
                              hipStream_t stream) {
    const float* x  = (const float*)d_in[0];
    const float* Wq = (const float*)d_in[1];
    const float* Wk = (const float*)d_in[2];
    const float* Wv = (const float*)d_in[3];
    const float* Wp = (const float*)d_in[4];
    const float* bp = (const float*)d_in[5];
    float* out = (float*)d_out;

    const size_t SZ  = (size_t)M_ * D_;      // 8388608
    const size_t WSZ = (size_t)D_ * D_;      // 1048576
    unsigned short* ws = (unsigned short*)d_ws;
    unsigned short* XB  = ws;                 // also Y after qkv
    unsigned short* WQB = XB  + SZ;
    unsigned short* WKB = WQB + WSZ;
    unsigned short* WVB = WKB + WSZ;
    unsigned short* WPB = WVB + WSZ;
    unsigned short* Qw  = WPB + WSZ;
    unsigned short* Kw  = Qw + SZ;
    unsigned short* Vw  = Kw + SZ;
    unsigned short* Yw  = XB;                 // overlay: x_bf16 dead after qkv

    dim3 blk(256);
    cvt_kernel<<<dim3(SZ / 1024),  blk, 0, stream>>>(x,  XB);
    cvt_kernel<<<dim3(WSZ / 1024), blk, 0, stream>>>(Wq, WQB);
    cvt_kernel<<<dim3(WSZ / 1024), blk, 0, stream>>>(Wk, WKB);
    cvt_kernel<<<dim3(WSZ / 1024), blk, 0, stream>>>(Wv, WVB);
    cvt_kernel<<<dim3(WSZ / 1024), blk, 0, stream>>>(Wp, WPB);

    qkv_kernel <<<dim3(M_ / 128, 24), blk, 0, stream>>>(XB, WQB, WKB, WVB, Qw, Kw, Vw);
    attn_kernel<<<dim3(B_ * H_, 16), blk, 0, stream>>>(Qw, Kw, Vw, Yw);
    proj_kernel<<<dim3(M_ / 128, D_ / 128), blk, 0, stream>>>(Yw, WPB, bp, out);
}